// Round 1
// baseline (1352.406 us; speedup 1.0000x reference)
//
#include <hip/hip_runtime.h>
#include <cstdint>

#define B_  2
#define L_  2048
#define D_  1024
#define H_  16
#define HD_ 64

// ---------------------------------------------------------------------------
// Projection GEMM with fused xPos.
// grid (L_/64, B_*H_), block 256.
// out[b,h,l,e] = sum_d X[b,l,d] * W[h,d,e]; mode 0: xpos(q), 1: xpos(k, 1/scale), 2: none (v)
// ---------------------------------------------------------------------------
__global__ __launch_bounds__(256) void proj_kernel(
    const float* __restrict__ X, const float* __restrict__ W,
    float* __restrict__ out, int mode)
{
  __shared__ float As[16][68];   // [k][m], pad 68 -> 272B row stride (16B-aligned, conflict-free writes)
  __shared__ float Bs[16][64];   // [k][n]
  const int tid = threadIdx.x;
  const int tx = tid & 15, ty = tid >> 4;
  const int l0 = blockIdx.x * 64;
  const int b  = blockIdx.y >> 4, h = blockIdx.y & 15;
  const float* A  = X + (size_t)(b * L_ + l0) * D_;
  const float* Bm = W + (size_t)h * D_ * HD_;
  const int arow = tid >> 2, akc = (tid & 3) << 2;     // A: 64 rows x 16 k
  const int brow = tid >> 4, bcol = (tid & 15) << 2;   // B: 16 k x 64 n
  float acc[4][4] = {};
  for (int k0 = 0; k0 < D_; k0 += 16) {
    float4 av = *(const float4*)(A + (size_t)arow * D_ + k0 + akc);
    float4 bv = *(const float4*)(Bm + (size_t)(k0 + brow) * HD_ + bcol);
    __syncthreads();
    As[akc + 0][arow] = av.x;
    As[akc + 1][arow] = av.y;
    As[akc + 2][arow] = av.z;
    As[akc + 3][arow] = av.w;
    *(float4*)&Bs[brow][bcol] = bv;
    __syncthreads();
#pragma unroll
    for (int kk = 0; kk < 16; ++kk) {
      float4 a  = *(const float4*)&As[kk][ty << 2];
      float4 bb = *(const float4*)&Bs[kk][tx << 2];
      float ar[4] = {a.x, a.y, a.z, a.w};
      float br[4] = {bb.x, bb.y, bb.z, bb.w};
#pragma unroll
      for (int r = 0; r < 4; ++r)
#pragma unroll
        for (int c = 0; c < 4; ++c) acc[r][c] += ar[r] * br[c];
    }
  }
  if (mode < 2) {
    // xPos: pairs (2i, 2i+1); this thread's 4 cols = pairs i = 2*tx, 2*tx+1
#pragma unroll
    for (int r = 0; r < 4; ++r) {
      const int l = l0 + (ty << 2) + r;
      float power = (float)(l - (L_ / 2)) * (1.0f / 512.0f);
      if (mode == 1) power = -power;   // downscale -> base^(-power)
#pragma unroll
      for (int p = 0; p < 2; ++p) {
        const int i = (tx << 1) + p;
        const float base = (2.0f * (float)i + 0.4f * (float)HD_) / (1.4f * (float)HD_);
        const float lsc = exp2f(power * log2f(base));
        const float inv_freq = exp2f(-(float)i * (13.287712379549449f / 32.0f)); // 10000^(-i/32)
        const float ang = (float)l * inv_freq;
        float s, c;
        sincosf(ang, &s, &c);
        s *= lsc; c *= lsc;
        const float x0 = acc[r][2 * p], x1 = acc[r][2 * p + 1];
        acc[r][2 * p]     = x0 * c - x1 * s;
        acc[r][2 * p + 1] = x1 * c + x0 * s;
      }
    }
  }
#pragma unroll
  for (int r = 0; r < 4; ++r) {
    const int l = l0 + (ty << 2) + r;
    float4 st = {acc[r][0], acc[r][1], acc[r][2], acc[r][3]};
    *(float4*)(out + ((size_t)(b * H_ + h) * L_ + l) * HD_ + (tx << 2)) = st;
  }
}

// ---------------------------------------------------------------------------
// gate = silu(X @ Wt^T + bias).  X: (M=B*L, D), Wt: (D, D) row-major (N-major rows).
// grid (M/64, D_/64), block 256.
// ---------------------------------------------------------------------------
__global__ __launch_bounds__(256) void gate_kernel(
    const float* __restrict__ X, const float* __restrict__ Wt,
    const float* __restrict__ bias, float* __restrict__ out)
{
  __shared__ float As[16][68];   // [k][m]
  __shared__ float Bs[16][68];   // [k][n]
  const int tid = threadIdx.x;
  const int tx = tid & 15, ty = tid >> 4;
  const int m0 = blockIdx.x * 64, n0 = blockIdx.y * 64;
  const int row = tid >> 2, kc = (tid & 3) << 2;
  float acc[4][4] = {};
  for (int k0 = 0; k0 < D_; k0 += 16) {
    float4 av = *(const float4*)(X  + (size_t)(m0 + row) * D_ + k0 + kc);
    float4 bv = *(const float4*)(Wt + (size_t)(n0 + row) * D_ + k0 + kc);
    __syncthreads();
    As[kc + 0][row] = av.x; As[kc + 1][row] = av.y; As[kc + 2][row] = av.z; As[kc + 3][row] = av.w;
    Bs[kc + 0][row] = bv.x; Bs[kc + 1][row] = bv.y; Bs[kc + 2][row] = bv.z; Bs[kc + 3][row] = bv.w;
    __syncthreads();
#pragma unroll
    for (int kk = 0; kk < 16; ++kk) {
      float4 a  = *(const float4*)&As[kk][ty << 2];
      float4 bb = *(const float4*)&Bs[kk][tx << 2];
      float ar[4] = {a.x, a.y, a.z, a.w};
      float br[4] = {bb.x, bb.y, bb.z, bb.w};
#pragma unroll
      for (int r = 0; r < 4; ++r)
#pragma unroll
        for (int c = 0; c < 4; ++c) acc[r][c] += ar[r] * br[c];
    }
  }
#pragma unroll
  for (int r = 0; r < 4; ++r) {
    float4 st;
    float* stp = &st.x;
#pragma unroll
    for (int c = 0; c < 4; ++c) {
      const int j = n0 + (tx << 2) + c;
      const float x = acc[r][c] + bias[j];
      stp[c] = x / (1.0f + expf(-x));   // silu
    }
    *(float4*)(out + (size_t)(m0 + (ty << 2) + r) * D_ + n0 + (tx << 2)) = st;
  }
}

// ---------------------------------------------------------------------------
// Final: out = (Rn .* G) @ Wt^T + bias.   Same structure as gate_kernel, A staged as product.
// ---------------------------------------------------------------------------
__global__ __launch_bounds__(256) void final_kernel(
    const float* __restrict__ Rn, const float* __restrict__ G,
    const float* __restrict__ Wt, const float* __restrict__ bias,
    float* __restrict__ out)
{
  __shared__ float As[16][68];
  __shared__ float Bs[16][68];
  const int tid = threadIdx.x;
  const int tx = tid & 15, ty = tid >> 4;
  const int m0 = blockIdx.x * 64, n0 = blockIdx.y * 64;
  const int row = tid >> 2, kc = (tid & 3) << 2;
  float acc[4][4] = {};
  for (int k0 = 0; k0 < D_; k0 += 16) {
    float4 ra = *(const float4*)(Rn + (size_t)(m0 + row) * D_ + k0 + kc);
    float4 ga = *(const float4*)(G  + (size_t)(m0 + row) * D_ + k0 + kc);
    float4 bv = *(const float4*)(Wt + (size_t)(n0 + row) * D_ + k0 + kc);
    __syncthreads();
    As[kc + 0][row] = ra.x * ga.x; As[kc + 1][row] = ra.y * ga.y;
    As[kc + 2][row] = ra.z * ga.z; As[kc + 3][row] = ra.w * ga.w;
    Bs[kc + 0][row] = bv.x; Bs[kc + 1][row] = bv.y; Bs[kc + 2][row] = bv.z; Bs[kc + 3][row] = bv.w;
    __syncthreads();
#pragma unroll
    for (int kk = 0; kk < 16; ++kk) {
      float4 a  = *(const float4*)&As[kk][ty << 2];
      float4 bb = *(const float4*)&Bs[kk][tx << 2];
      float ar[4] = {a.x, a.y, a.z, a.w};
      float br[4] = {bb.x, bb.y, bb.z, bb.w};
#pragma unroll
      for (int r = 0; r < 4; ++r)
#pragma unroll
        for (int c = 0; c < 4; ++c) acc[r][c] += ar[r] * br[c];
    }
  }
#pragma unroll
  for (int r = 0; r < 4; ++r) {
    float4 st;
    float* stp = &st.x;
#pragma unroll
    for (int c = 0; c < 4; ++c) {
      const int j = n0 + (tx << 2) + c;
      stp[c] = acc[r][c] + bias[j];
    }
    *(float4*)(out + (size_t)(m0 + (ty << 2) + r) * D_ + n0 + (tx << 2)) = st;
  }
}

// ---------------------------------------------------------------------------
// Retention attention + fused GroupNorm.
// grid (L_/64, B_*H_), block 256.  Q tile 64 rows; K/V tiles 32 wide (causal).
// ret[n,:] = sum_{s<=n} gamma^(n-s) (q_n . k_s) v_s ; then per-row groupnorm over hd.
// Output layout (B, L, H, hd) == (B, L, D) after reshape.
// ---------------------------------------------------------------------------
__global__ __launch_bounds__(256) void attn_kernel(
    const float* __restrict__ q, const float* __restrict__ k,
    const float* __restrict__ v, float* __restrict__ retn)
{
  __shared__ float Qt[64][68];   // [e][m]  (transposed), stride 272B: aligned float4 rows
  __shared__ float Kt[64][36];   // [e][n]  n < 32
  __shared__ float Vs[32][68];   // [s][e]
  __shared__ float St[32][68];   // [s][m]  (S transposed)
  const int tid = threadIdx.x;
  const int tx = tid & 15, ty = tid >> 4;
  const int l0 = blockIdx.x * 64;
  const int bh = blockIdx.y;
  const int b  = bh >> 4, h = bh & 15;
  // gammas: 1 - exp(linspace(ln(1/32), ln(1/512), 16))
  const float lo   = -3.4657359027997265f;
  const float step = -0.18483924813542476f;   // (ln(1/512)-ln(1/32))/15
  const float gamma = 1.0f - expf(lo + (float)h * step);
  const float lg2g  = log2f(gamma);
  const size_t base = (size_t)bh * L_ * HD_;

  // load Q tile (64 x 64) transposed into Qt
  {
    const int rr = tid >> 4, e4 = (tid & 15) << 2;
#pragma unroll
    for (int it = 0; it < 4; ++it) {
      const int rw = rr + it * 16;
      float4 qa = *(const float4*)(q + base + (size_t)(l0 + rw) * HD_ + e4);
      Qt[e4 + 0][rw] = qa.x; Qt[e4 + 1][rw] = qa.y; Qt[e4 + 2][rw] = qa.z; Qt[e4 + 3][rw] = qa.w;
    }
  }

  float racc[4][4] = {};
  const int n_st = 2 * blockIdx.x + 1;    // s-tiles of 32 covering s <= l0+63
  for (int st = 0; st <= n_st; ++st) {
    const int s0 = st * 32;
    __syncthreads();   // previous iteration's readers done (also covers Qt before first use)
    {
      const int rr = tid >> 4, e4 = (tid & 15) << 2;
#pragma unroll
      for (int it = 0; it < 2; ++it) {
        const int rw = rr + it * 16;   // 0..31
        float4 ka = *(const float4*)(k + base + (size_t)(s0 + rw) * HD_ + e4);
        float4 va = *(const float4*)(v + base + (size_t)(s0 + rw) * HD_ + e4);
        Kt[e4 + 0][rw] = ka.x; Kt[e4 + 1][rw] = ka.y; Kt[e4 + 2][rw] = ka.z; Kt[e4 + 3][rw] = ka.w;
        Vs[rw][e4 + 0] = va.x; Vs[rw][e4 + 1] = va.y; Vs[rw][e4 + 2] = va.z; Vs[rw][e4 + 3] = va.w;
      }
    }
    __syncthreads();
    // S = Q . K^T  (64 x 32): thread -> rows 4ty..+3, cols 2tx..+1
    float sacc[4][2] = {};
#pragma unroll 16
    for (int e = 0; e < 64; ++e) {
      float4 a = *(const float4*)&Qt[e][ty << 2];
      float2 bb = *(const float2*)&Kt[e][tx << 1];
      sacc[0][0] += a.x * bb.x; sacc[0][1] += a.x * bb.y;
      sacc[1][0] += a.y * bb.x; sacc[1][1] += a.y * bb.y;
      sacc[2][0] += a.z * bb.x; sacc[2][1] += a.z * bb.y;
      sacc[3][0] += a.w * bb.x; sacc[3][1] += a.w * bb.y;
    }
    // decay + store S transposed
#pragma unroll
    for (int r = 0; r < 4; ++r) {
      const int n = l0 + (ty << 2) + r;
#pragma unroll
      for (int c = 0; c < 2; ++c) {
        const int d = n - (s0 + (tx << 1) + c);
        const float w = (d >= 0) ? exp2f((float)d * lg2g) : 0.0f;
        St[(tx << 1) + c][(ty << 2) + r] = sacc[r][c] * w;
      }
    }
    __syncthreads();
    // ret += S . V  (64 x 64)
#pragma unroll 16
    for (int s = 0; s < 32; ++s) {
      float4 a  = *(const float4*)&St[s][ty << 2];
      float4 bb = *(const float4*)&Vs[s][tx << 2];
      racc[0][0] += a.x * bb.x; racc[0][1] += a.x * bb.y; racc[0][2] += a.x * bb.z; racc[0][3] += a.x * bb.w;
      racc[1][0] += a.y * bb.x; racc[1][1] += a.y * bb.y; racc[1][2] += a.y * bb.z; racc[1][3] += a.y * bb.w;
      racc[2][0] += a.z * bb.x; racc[2][1] += a.z * bb.y; racc[2][2] += a.z * bb.z; racc[2][3] += a.z * bb.w;
      racc[3][0] += a.w * bb.x; racc[3][1] += a.w * bb.y; racc[3][2] += a.w * bb.z; racc[3][3] += a.w * bb.w;
    }
  }

  // fused GroupNorm over hd=64 per row; partial sums via LDS (reuse Qt, Kt)
  __syncthreads();
#pragma unroll
  for (int r = 0; r < 4; ++r) {
    const int m = (ty << 2) + r;
    const float sm = racc[r][0] + racc[r][1] + racc[r][2] + racc[r][3];
    const float sq = racc[r][0] * racc[r][0] + racc[r][1] * racc[r][1]
                   + racc[r][2] * racc[r][2] + racc[r][3] * racc[r][3];
    Qt[m][tx] = sm;
    Kt[m][tx] = sq;
  }
  __syncthreads();
#pragma unroll
  for (int r = 0; r < 4; ++r) {
    const int m = (ty << 2) + r;
    float sm = 0.0f, sq = 0.0f;
#pragma unroll
    for (int j = 0; j < 16; ++j) { sm += Qt[m][j]; sq += Kt[m][j]; }
    const float mu  = sm * (1.0f / 64.0f);
    float var = sq * (1.0f / 64.0f) - mu * mu;
    var = fmaxf(var, 0.0f);
    const float inv = rsqrtf(var + 1e-5f);
    float4 stv;
    stv.x = (racc[r][0] - mu) * inv;
    stv.y = (racc[r][1] - mu) * inv;
    stv.z = (racc[r][2] - mu) * inv;
    stv.w = (racc[r][3] - mu) * inv;
    const int l = l0 + m;
    // (B, L, H, hd) layout -> contiguous (B, L, D)
    *(float4*)(retn + (size_t)(b * L_ + l) * D_ + h * HD_ + (tx << 2)) = stv;
  }
}

// ---------------------------------------------------------------------------
extern "C" void kernel_launch(void* const* d_in, const int* in_sizes, int n_in,
                              void* d_out, int out_size, void* d_ws, size_t ws_size,
                              hipStream_t stream)
{
  const float* query = (const float*)d_in[0];
  const float* key   = (const float*)d_in[1];
  const float* value = (const float*)d_in[2];
  const float* W_Q   = (const float*)d_in[3];
  const float* W_K   = (const float*)d_in[4];
  const float* W_V   = (const float*)d_in[5];
  const float* g_w   = (const float*)d_in[6];
  const float* g_b   = (const float*)d_in[7];
  const float* out_w = (const float*)d_in[8];
  const float* out_b = (const float*)d_in[9];
  float* out = (float*)d_out;

  // workspace: q, k, v (B,H,L,hd) + gate (B,L,D) + retn (B,L,D) = 80 MB
  const size_t per = (size_t)B_ * H_ * L_ * HD_;   // 4,194,304
  float* qb   = (float*)d_ws;
  float* kb   = qb + per;
  float* vb   = kb + per;
  float* gate = vb + per;
  float* retn = gate + per;

  dim3 blk(256);
  proj_kernel<<<dim3(L_ / 64, B_ * H_), blk, 0, stream>>>(query, W_Q, qb, 0);
  proj_kernel<<<dim3(L_ / 64, B_ * H_), blk, 0, stream>>>(key,   W_K, kb, 1);
  proj_kernel<<<dim3(L_ / 64, B_ * H_), blk, 0, stream>>>(value, W_V, vb, 2);
  gate_kernel<<<dim3(B_ * L_ / 64, D_ / 64), blk, 0, stream>>>(query, g_w, g_b, gate);
  attn_kernel<<<dim3(L_ / 64, B_ * H_), blk, 0, stream>>>(qb, kb, vb, retn);
  final_kernel<<<dim3(B_ * L_ / 64, D_ / 64), blk, 0, stream>>>(retn, gate, out_w, out_b, out);
}

// Round 2
// 861.466 us; speedup vs baseline: 1.5699x; 1.5699x over previous
//
#include <hip/hip_runtime.h>
#include <cstdint>

#define B_  2
#define L_  2048
#define D_  1024
#define H_  16
#define HD_ 64
#define M_  (B_*L_)   // 4096

typedef __attribute__((ext_vector_type(8))) short bf16x8;   // 8 bf16 = 4 VGPRs
typedef __attribute__((ext_vector_type(4))) float f32x4;

__device__ __forceinline__ unsigned short f2b(float x){
  union { float f; unsigned u; } a; a.f = x;
  unsigned r = a.u + 0x7FFFu + ((a.u >> 16) & 1u);   // RNE
  return (unsigned short)(r >> 16);
}
__device__ __forceinline__ float b2f(unsigned short u){
  union { unsigned u; float f; } a; a.u = ((unsigned)u) << 16; return a.f;
}

// ---------------------------------------------------------------------------
// fp32 -> bf16 elementwise cast (n multiple of 4)
// ---------------------------------------------------------------------------
__global__ __launch_bounds__(256) void cast_f2b_kernel(
    const float* __restrict__ src, unsigned short* __restrict__ dst, int n)
{
  int i = (blockIdx.x * 256 + threadIdx.x) * 4;
  if (i >= n) return;
  float4 v = *(const float4*)(src + i);
  ushort4 o; o.x = f2b(v.x); o.y = f2b(v.y); o.z = f2b(v.z); o.w = f2b(v.w);
  *(ushort4*)(dst + i) = o;
}

// ---------------------------------------------------------------------------
// W (h, d, e) fp32 -> Bt[(h*64+e)][d] bf16  (B^T layout, k-contiguous)
// grid (D/32, HD/32, H), block (32,8)
// ---------------------------------------------------------------------------
__global__ void transpose_w_kernel(const float* __restrict__ in,
                                   unsigned short* __restrict__ out)
{
  __shared__ float t[32][33];
  const int h = blockIdx.z;
  const int d0 = blockIdx.x * 32, e0 = blockIdx.y * 32;
  const int x = threadIdx.x;
  for (int yy = threadIdx.y; yy < 32; yy += 8)
    t[yy][x] = in[((size_t)h * D_ + d0 + yy) * HD_ + e0 + x];
  __syncthreads();
  for (int yy = threadIdx.y; yy < 32; yy += 8)
    out[((size_t)h * HD_ + e0 + yy) * D_ + d0 + x] = f2b(t[x][yy]);
}

// ---------------------------------------------------------------------------
// xPos tables: per (l, pair i): cos*scale, sin*scale (q) and /scale (k)
// grid 2048, block 32
// ---------------------------------------------------------------------------
__global__ void xpos_tables_kernel(float* __restrict__ ctq, float* __restrict__ stq,
                                   float* __restrict__ ctk, float* __restrict__ stk)
{
  const int l = blockIdx.x, i = threadIdx.x;
  const float base = (2.0f * (float)i + 0.4f * (float)HD_) / (1.4f * (float)HD_);
  const float p = (float)(l - L_ / 2) * (1.0f / 512.0f);
  const float sc = exp2f(p * log2f(base));
  const float invf = exp2f(-(float)i * (13.287712379549449f / 32.0f)); // 10000^{-i/32}
  float s, c; sincosf((float)l * invf, &s, &c);
  ctq[l * 32 + i] = c * sc;  stq[l * 32 + i] = s * sc;
  const float is = 1.0f / sc;
  ctk[l * 32 + i] = c * is;  stk[l * 32 + i] = s * is;
}

// ---------------------------------------------------------------------------
// bf16 MFMA GEMM: C(M_,1024) = A(M_,1024) @ Bt^T, Bt is (n,k) k-contiguous.
// 128x64 tile, 4 waves (2x2), mfma_f32_16x16x32_bf16, global_load_lds staging.
// mode 0: plain fp32 out; 1/2: xpos (tables) fp32 out; 3: silu+bias bf16 out;
// 4: +bias fp32 out.
// grid (M_/128, 1024/64) = (32,16), block 256
// ---------------------------------------------------------------------------
__global__ __launch_bounds__(256) void gemm_bf16_kernel(
    const unsigned short* __restrict__ A, const unsigned short* __restrict__ Bt,
    float* __restrict__ outF, unsigned short* __restrict__ outB,
    const float* __restrict__ ct, const float* __restrict__ st,
    const float* __restrict__ bias, int mode)
{
  __shared__ __align__(16) short As[128 * 32];  // [m][k] row-major, 8 KB
  __shared__ __align__(16) short Bs[64 * 32];   // [n][k] row-major, 4 KB
  const int tid = threadIdx.x;
  const int wave = tid >> 6, lane = tid & 63;
  const int wm = wave & 1, wn = wave >> 1;
  const int mlane = lane & 15, kgrp = lane >> 4;
  const int M0 = blockIdx.x * 128, N0 = blockIdx.y * 64;

  const int arow0 = wave * 32 + (lane >> 2);  // + t*16
  const int akc   = lane & 3;                  // 16B chunk within 64B row
  const int brow  = wave * 16 + (lane >> 2);
  const char* Ab = (const char*)A;
  const char* Bb = (const char*)Bt;

  f32x4 acc[4][2] = {};

  for (int K0 = 0; K0 < 1024; K0 += 32) {
    __syncthreads();
#pragma unroll
    for (int t = 0; t < 2; ++t) {
      const char* g = Ab + ((size_t)(M0 + arow0 + t * 16) * 1024 + K0 + akc * 8) * 2;
      __builtin_amdgcn_global_load_lds(
          (const __attribute__((address_space(1))) void*)g,
          (__attribute__((address_space(3))) void*)((char*)As + (wave * 2 + t) * 1024 + lane * 16),
          16, 0, 0);
    }
    {
      const char* g = Bb + ((size_t)(N0 + brow) * 1024 + K0 + akc * 8) * 2;
      __builtin_amdgcn_global_load_lds(
          (const __attribute__((address_space(1))) void*)g,
          (__attribute__((address_space(3))) void*)((char*)Bs + wave * 1024 + lane * 16),
          16, 0, 0);
    }
    __syncthreads();
    bf16x8 af[4], bfr[2];
#pragma unroll
    for (int tm = 0; tm < 4; ++tm)
      af[tm] = *(const bf16x8*)&As[(wm * 64 + tm * 16 + mlane) * 32 + kgrp * 8];
#pragma unroll
    for (int tn = 0; tn < 2; ++tn)
      bfr[tn] = *(const bf16x8*)&Bs[(wn * 32 + tn * 16 + mlane) * 32 + kgrp * 8];
#pragma unroll
    for (int tm = 0; tm < 4; ++tm)
#pragma unroll
      for (int tn = 0; tn < 2; ++tn)
        acc[tm][tn] = __builtin_amdgcn_mfma_f32_16x16x32_bf16(af[tm], bfr[tn], acc[tm][tn], 0, 0, 0);
  }

  // epilogue: C/D layout col=lane&15, row=(lane>>4)*4+reg  [verified m89/m91]
#pragma unroll
  for (int tm = 0; tm < 4; ++tm)
#pragma unroll
    for (int tn = 0; tn < 2; ++tn) {
      f32x4 v = acc[tm][tn];
#pragma unroll
      for (int r = 0; r < 4; ++r) {
        const int grow = M0 + wm * 64 + tm * 16 + (lane >> 4) * 4 + r;
        const int gcol = N0 + wn * 32 + tn * 16 + mlane;
        float val = v[r];
        if (mode <= 2) {
          if (mode) {   // xpos rotate: pair partner lives in lane^1 (col parity == lane parity)
            const float partner = __shfl_xor(val, 1);
            const int l = grow & (L_ - 1);
            const int i = (gcol >> 1) & 31;
            const float c = ct[l * 32 + i], s = st[l * 32 + i];
            val = (gcol & 1) ? (val * c + partner * s) : (val * c - partner * s);
          }
          outF[(size_t)grow * D_ + gcol] = val;
        } else if (mode == 3) {
          const float x = val + bias[gcol];
          outB[(size_t)grow * D_ + gcol] = f2b(x / (1.0f + expf(-x)));
        } else {
          outF[(size_t)grow * D_ + gcol] = val + bias[gcol];
        }
      }
    }
}

// ---------------------------------------------------------------------------
// Retention attention + fused GroupNorm + gate-multiply (fp32 compute).
// q,k,v in (B, L, H, hd) fp32 (row stride D_). gate bf16 (B,L,D).
// Writes Abuf bf16 (B,L,D) = groupnorm(ret) * gate  -> A of final GEMM.
// grid (L_/64, B_*H_), block 256.
// ---------------------------------------------------------------------------
__global__ __launch_bounds__(256) void attn_kernel(
    const float* __restrict__ q, const float* __restrict__ k,
    const float* __restrict__ v, const unsigned short* __restrict__ gate,
    unsigned short* __restrict__ Abuf)
{
  __shared__ float Qt[64][68];   // [e][m] transposed
  __shared__ float Kt[64][36];   // [e][n]
  __shared__ float Vs[32][68];   // [s][e]
  __shared__ float St[32][68];   // [s][m]
  const int tid = threadIdx.x;
  const int tx = tid & 15, ty = tid >> 4;
  const int l0 = blockIdx.x * 64;
  const int bh = blockIdx.y;
  const int b  = bh >> 4, h = bh & 15;
  const float lo   = -3.4657359027997265f;
  const float step = -0.18483924813542476f;
  const float gamma = 1.0f - expf(lo + (float)h * step);
  const float lg2g  = log2f(gamma);
  const size_t base = (size_t)(b * L_) * D_ + h * HD_;   // row stride D_

  {
    const int rr = tid >> 4, e4 = (tid & 15) << 2;
#pragma unroll
    for (int it = 0; it < 4; ++it) {
      const int rw = rr + it * 16;
      float4 qa = *(const float4*)(q + base + (size_t)(l0 + rw) * D_ + e4);
      Qt[e4 + 0][rw] = qa.x; Qt[e4 + 1][rw] = qa.y; Qt[e4 + 2][rw] = qa.z; Qt[e4 + 3][rw] = qa.w;
    }
  }

  float racc[4][4] = {};
  const int n_st = 2 * blockIdx.x + 1;
  for (int st = 0; st <= n_st; ++st) {
    const int s0 = st * 32;
    __syncthreads();
    {
      const int rr = tid >> 4, e4 = (tid & 15) << 2;
#pragma unroll
      for (int it = 0; it < 2; ++it) {
        const int rw = rr + it * 16;
        float4 ka = *(const float4*)(k + base + (size_t)(s0 + rw) * D_ + e4);
        float4 va = *(const float4*)(v + base + (size_t)(s0 + rw) * D_ + e4);
        Kt[e4 + 0][rw] = ka.x; Kt[e4 + 1][rw] = ka.y; Kt[e4 + 2][rw] = ka.z; Kt[e4 + 3][rw] = ka.w;
        Vs[rw][e4 + 0] = va.x; Vs[rw][e4 + 1] = va.y; Vs[rw][e4 + 2] = va.z; Vs[rw][e4 + 3] = va.w;
      }
    }
    __syncthreads();
    float sacc[4][2] = {};
#pragma unroll 16
    for (int e = 0; e < 64; ++e) {
      float4 a = *(const float4*)&Qt[e][ty << 2];
      float2 bb = *(const float2*)&Kt[e][tx << 1];
      sacc[0][0] += a.x * bb.x; sacc[0][1] += a.x * bb.y;
      sacc[1][0] += a.y * bb.x; sacc[1][1] += a.y * bb.y;
      sacc[2][0] += a.z * bb.x; sacc[2][1] += a.z * bb.y;
      sacc[3][0] += a.w * bb.x; sacc[3][1] += a.w * bb.y;
    }
#pragma unroll
    for (int r = 0; r < 4; ++r) {
      const int n = l0 + (ty << 2) + r;
#pragma unroll
      for (int c = 0; c < 2; ++c) {
        const int d = n - (s0 + (tx << 1) + c);
        const float w = (d >= 0) ? exp2f((float)d * lg2g) : 0.0f;
        St[(tx << 1) + c][(ty << 2) + r] = sacc[r][c] * w;
      }
    }
    __syncthreads();
#pragma unroll 16
    for (int s = 0; s < 32; ++s) {
      float4 a  = *(const float4*)&St[s][ty << 2];
      float4 bb = *(const float4*)&Vs[s][tx << 2];
      racc[0][0] += a.x * bb.x; racc[0][1] += a.x * bb.y; racc[0][2] += a.x * bb.z; racc[0][3] += a.x * bb.w;
      racc[1][0] += a.y * bb.x; racc[1][1] += a.y * bb.y; racc[1][2] += a.y * bb.z; racc[1][3] += a.y * bb.w;
      racc[2][0] += a.z * bb.x; racc[2][1] += a.z * bb.y; racc[2][2] += a.z * bb.z; racc[2][3] += a.z * bb.w;
      racc[3][0] += a.w * bb.x; racc[3][1] += a.w * bb.y; racc[3][2] += a.w * bb.z; racc[3][3] += a.w * bb.w;
    }
  }

  __syncthreads();
#pragma unroll
  for (int r = 0; r < 4; ++r) {
    const int m = (ty << 2) + r;
    const float sm = racc[r][0] + racc[r][1] + racc[r][2] + racc[r][3];
    const float sq = racc[r][0] * racc[r][0] + racc[r][1] * racc[r][1]
                   + racc[r][2] * racc[r][2] + racc[r][3] * racc[r][3];
    Qt[m][tx] = sm;
    Kt[m][tx] = sq;
  }
  __syncthreads();
#pragma unroll
  for (int r = 0; r < 4; ++r) {
    const int m = (ty << 2) + r;
    float sm = 0.0f, sq = 0.0f;
#pragma unroll
    for (int j = 0; j < 16; ++j) { sm += Qt[m][j]; sq += Kt[m][j]; }
    const float mu  = sm * (1.0f / 64.0f);
    float var = sq * (1.0f / 64.0f) - mu * mu;
    var = fmaxf(var, 0.0f);
    const float inv = rsqrtf(var + 1e-5f);
    const int l = l0 + m;
    const size_t orow = (size_t)(b * L_ + l) * D_ + h * HD_ + (tx << 2);
    ushort4 g4 = *(const ushort4*)(gate + orow);
    ushort4 ob;
    ob.x = f2b((racc[r][0] - mu) * inv * b2f(g4.x));
    ob.y = f2b((racc[r][1] - mu) * inv * b2f(g4.y));
    ob.z = f2b((racc[r][2] - mu) * inv * b2f(g4.z));
    ob.w = f2b((racc[r][3] - mu) * inv * b2f(g4.w));
    *(ushort4*)(Abuf + orow) = ob;
  }
}

// ---------------------------------------------------------------------------
extern "C" void kernel_launch(void* const* d_in, const int* in_sizes, int n_in,
                              void* d_out, int out_size, void* d_ws, size_t ws_size,
                              hipStream_t stream)
{
  const float* query = (const float*)d_in[0];
  const float* key   = (const float*)d_in[1];
  const float* value = (const float*)d_in[2];
  const float* W_Q   = (const float*)d_in[3];
  const float* W_K   = (const float*)d_in[4];
  const float* W_V   = (const float*)d_in[5];
  const float* g_w   = (const float*)d_in[6];
  const float* g_b   = (const float*)d_in[7];
  const float* out_w = (const float*)d_in[8];
  const float* out_b = (const float*)d_in[9];
  float* out = (float*)d_out;

  const size_t MD = (size_t)M_ * D_;    // 4M elements
  const size_t DD = (size_t)D_ * D_;    // 1M elements
  unsigned short* Xqb   = (unsigned short*)d_ws;  // bf16 buffers
  unsigned short* Xkb   = Xqb + MD;
  unsigned short* Xvb   = Xkb + MD;
  unsigned short* WQt   = Xvb + MD;
  unsigned short* WKt   = WQt + DD;
  unsigned short* WVt   = WKt + DD;
  unsigned short* gwb   = WVt + DD;
  unsigned short* owb   = gwb + DD;
  unsigned short* gateB = owb + DD;
  unsigned short* AbufB = gateB + MD;
  float* qf  = (float*)(AbufB + MD);               // fp32 buffers
  float* kf  = qf + MD;
  float* vf  = kf + MD;
  float* ctq = vf + MD;
  float* stq = ctq + 2048 * 32;
  float* ctk = stq + 2048 * 32;
  float* stk = ctk + 2048 * 32;

  cast_f2b_kernel<<<4096, 256, 0, stream>>>(query, Xqb, (int)MD);
  cast_f2b_kernel<<<4096, 256, 0, stream>>>(key,   Xkb, (int)MD);
  cast_f2b_kernel<<<4096, 256, 0, stream>>>(value, Xvb, (int)MD);
  cast_f2b_kernel<<<1024, 256, 0, stream>>>(g_w,   gwb, (int)DD);
  cast_f2b_kernel<<<1024, 256, 0, stream>>>(out_w, owb, (int)DD);
  transpose_w_kernel<<<dim3(32, 2, 16), dim3(32, 8), 0, stream>>>(W_Q, WQt);
  transpose_w_kernel<<<dim3(32, 2, 16), dim3(32, 8), 0, stream>>>(W_K, WKt);
  transpose_w_kernel<<<dim3(32, 2, 16), dim3(32, 8), 0, stream>>>(W_V, WVt);
  xpos_tables_kernel<<<2048, 32, 0, stream>>>(ctq, stq, ctk, stk);

  dim3 gg(M_ / 128, D_ / 64);
  gemm_bf16_kernel<<<gg, 256, 0, stream>>>(Xqb, WQt, qf, nullptr, ctq, stq, nullptr, 1);
  gemm_bf16_kernel<<<gg, 256, 0, stream>>>(Xkb, WKt, kf, nullptr, ctk, stk, nullptr, 2);
  gemm_bf16_kernel<<<gg, 256, 0, stream>>>(Xvb, WVt, vf, nullptr, nullptr, nullptr, nullptr, 0);
  gemm_bf16_kernel<<<gg, 256, 0, stream>>>(Xqb, gwb, nullptr, gateB, nullptr, nullptr, g_b, 3);

  attn_kernel<<<dim3(L_ / 64, B_ * H_), 256, 0, stream>>>(qf, kf, vf, gateB, AbufB);

  gemm_bf16_kernel<<<gg, 256, 0, stream>>>(AbufB, owb, out, nullptr, nullptr, nullptr, out_b, 4);
}

// Round 3
// 328.600 us; speedup vs baseline: 4.1157x; 2.6216x over previous
//
#include <hip/hip_runtime.h>
#include <cstdint>

#define B_  2
#define L_  2048
#define D_  1024
#define H_  16
#define HD_ 64
#define M_  (B_*L_)   // 4096

typedef __attribute__((ext_vector_type(8))) short bf16x8;   // 8 bf16 = 4 VGPRs
typedef __attribute__((ext_vector_type(4))) float f32x4;

__device__ __forceinline__ unsigned short f2b(float x){
  union { float f; unsigned u; } a; a.f = x;
  unsigned r = a.u + 0x7FFFu + ((a.u >> 16) & 1u);   // RNE
  return (unsigned short)(r >> 16);
}
__device__ __forceinline__ float b2f(unsigned short u){
  union { unsigned u; float f; } a; a.u = ((unsigned)u) << 16; return a.f;
}

// ---------------------------------------------------------------------------
// fp32 -> bf16 elementwise cast (n multiple of 4)
// ---------------------------------------------------------------------------
__global__ __launch_bounds__(256) void cast_f2b_kernel(
    const float* __restrict__ src, unsigned short* __restrict__ dst, int n)
{
  int i = (blockIdx.x * 256 + threadIdx.x) * 4;
  if (i >= n) return;
  float4 v = *(const float4*)(src + i);
  ushort4 o; o.x = f2b(v.x); o.y = f2b(v.y); o.z = f2b(v.z); o.w = f2b(v.w);
  *(ushort4*)(dst + i) = o;
}

// ---------------------------------------------------------------------------
// W (h, d, e) fp32 -> Bt[(h*64+e)][d] bf16  (B^T layout, k-contiguous)
// ---------------------------------------------------------------------------
__global__ void transpose_w_kernel(const float* __restrict__ in,
                                   unsigned short* __restrict__ out)
{
  __shared__ float t[32][33];
  const int h = blockIdx.z;
  const int d0 = blockIdx.x * 32, e0 = blockIdx.y * 32;
  const int x = threadIdx.x;
  for (int yy = threadIdx.y; yy < 32; yy += 8)
    t[yy][x] = in[((size_t)h * D_ + d0 + yy) * HD_ + e0 + x];
  __syncthreads();
  for (int yy = threadIdx.y; yy < 32; yy += 8)
    out[((size_t)h * HD_ + e0 + yy) * D_ + d0 + x] = f2b(t[x][yy]);
}

// ---------------------------------------------------------------------------
// xPos tables
// ---------------------------------------------------------------------------
__global__ void xpos_tables_kernel(float* __restrict__ ctq, float* __restrict__ stq,
                                   float* __restrict__ ctk, float* __restrict__ stk)
{
  const int l = blockIdx.x, i = threadIdx.x;
  const float base = (2.0f * (float)i + 0.4f * (float)HD_) / (1.4f * (float)HD_);
  const float p = (float)(l - L_ / 2) * (1.0f / 512.0f);
  const float sc = exp2f(p * log2f(base));
  const float invf = exp2f(-(float)i * (13.287712379549449f / 32.0f));
  float s, c; sincosf((float)l * invf, &s, &c);
  ctq[l * 32 + i] = c * sc;  stq[l * 32 + i] = s * sc;
  const float is = 1.0f / sc;
  ctk[l * 32 + i] = c * is;  stk[l * 32 + i] = s * is;
}

// ---------------------------------------------------------------------------
// bf16 MFMA GEMM: C = A @ Bt^T (both k-contiguous, K=1024).
// modes: 0 plain->bf16; 1/2 xpos->bf16; 3 silu+bias->bf16; 4 +bias->fp32
// grid (M/128, N/64), block 256, ldc = output row stride
// ---------------------------------------------------------------------------
__global__ __launch_bounds__(256) void gemm_bf16_kernel(
    const unsigned short* __restrict__ A, const unsigned short* __restrict__ Bt,
    float* __restrict__ outF, unsigned short* __restrict__ outB,
    const float* __restrict__ ct, const float* __restrict__ st,
    const float* __restrict__ bias, int mode, int ldc)
{
  __shared__ __align__(16) short As[128 * 32];
  __shared__ __align__(16) short Bs[64 * 32];
  const int tid = threadIdx.x;
  const int wave = tid >> 6, lane = tid & 63;
  const int wm = wave & 1, wn = wave >> 1;
  const int mlane = lane & 15, kgrp = lane >> 4;
  const int M0 = blockIdx.x * 128, N0 = blockIdx.y * 64;

  const int arow0 = wave * 32 + (lane >> 2);
  const int akc   = lane & 3;
  const int brow  = wave * 16 + (lane >> 2);
  const char* Ab = (const char*)A;
  const char* Bb = (const char*)Bt;

  f32x4 acc[4][2] = {};

  for (int K0 = 0; K0 < 1024; K0 += 32) {
    __syncthreads();
#pragma unroll
    for (int t = 0; t < 2; ++t) {
      const char* g = Ab + ((size_t)(M0 + arow0 + t * 16) * 1024 + K0 + akc * 8) * 2;
      __builtin_amdgcn_global_load_lds(
          (const __attribute__((address_space(1))) void*)g,
          (__attribute__((address_space(3))) void*)((char*)As + (wave * 2 + t) * 1024 + lane * 16),
          16, 0, 0);
    }
    {
      const char* g = Bb + ((size_t)(N0 + brow) * 1024 + K0 + akc * 8) * 2;
      __builtin_amdgcn_global_load_lds(
          (const __attribute__((address_space(1))) void*)g,
          (__attribute__((address_space(3))) void*)((char*)Bs + wave * 1024 + lane * 16),
          16, 0, 0);
    }
    __syncthreads();
    bf16x8 af[4], bfr[2];
#pragma unroll
    for (int tm = 0; tm < 4; ++tm)
      af[tm] = *(const bf16x8*)&As[(wm * 64 + tm * 16 + mlane) * 32 + kgrp * 8];
#pragma unroll
    for (int tn = 0; tn < 2; ++tn)
      bfr[tn] = *(const bf16x8*)&Bs[(wn * 32 + tn * 16 + mlane) * 32 + kgrp * 8];
#pragma unroll
    for (int tm = 0; tm < 4; ++tm)
#pragma unroll
      for (int tn = 0; tn < 2; ++tn)
        acc[tm][tn] = __builtin_amdgcn_mfma_f32_16x16x32_bf16(af[tm], bfr[tn], acc[tm][tn], 0, 0, 0);
  }

#pragma unroll
  for (int tm = 0; tm < 4; ++tm)
#pragma unroll
    for (int tn = 0; tn < 2; ++tn) {
      f32x4 v = acc[tm][tn];
#pragma unroll
      for (int r = 0; r < 4; ++r) {
        const int grow = M0 + wm * 64 + tm * 16 + (lane >> 4) * 4 + r;
        const int gcol = N0 + wn * 32 + tn * 16 + mlane;
        float val = v[r];
        if (mode == 1 || mode == 2) {
          const float partner = __shfl_xor(val, 1);
          const int l = grow & (L_ - 1);
          const int i = (gcol >> 1) & 31;
          const float c = ct[l * 32 + i], s = st[l * 32 + i];
          val = (gcol & 1) ? (val * c + partner * s) : (val * c - partner * s);
          outB[(size_t)grow * ldc + gcol] = f2b(val);
        } else if (mode == 0) {
          outB[(size_t)grow * ldc + gcol] = f2b(val);
        } else if (mode == 3) {
          const float x = val + bias[gcol];
          outB[(size_t)grow * ldc + gcol] = f2b(x / (1.0f + expf(-x)));
        } else {
          outF[(size_t)grow * ldc + gcol] = val + bias[gcol];
        }
      }
    }
}

// ---------------------------------------------------------------------------
// MFMA retention attention + fused GroupNorm + gate.
// q,k: (B*L, D) bf16. vt: vt[(h*64+e)*4096 + b*2048 + l] bf16.
// gate: (B*L,D) bf16. Abuf out bf16.
// grid (L_/128, B_*H_), block 256 (4 waves x 32 Q-rows).
// LDS tiles XOR-chunk-swizzled: addr = row*128 + ((chunk^(row&7))<<4)
// ---------------------------------------------------------------------------
#define QS_OFF 0
#define KS_OFF 16384
#define VT_OFF 24576
#define PS_OFF 32768

__global__ __launch_bounds__(256) void attn_mfma_kernel(
    const unsigned short* __restrict__ qg, const unsigned short* __restrict__ kg,
    const unsigned short* __restrict__ vtg, const unsigned short* __restrict__ gate,
    unsigned short* __restrict__ Abuf)
{
  __shared__ __align__(16) char smem[49152];
  const int tid = threadIdx.x, wave = tid >> 6, lane = tid & 63;
  const int mlane = lane & 15, kgrp = lane >> 4;
  const int l0 = blockIdx.x * 128;
  const int bh = blockIdx.y, b = bh >> 4, h = bh & 15;

  const float lo   = -3.4657359027997265f;
  const float step = -0.18483924814931877f;
  const float gamma = 1.0f - expf(lo + (float)h * step);
  const float lg2g  = log2f(gamma);

  const int rl = lane >> 3, csel = lane & 7;   // staging: row-in-group, chunk slot

  // ---- stage Q (128 rows x 64 bf16, swizzled) ----
#pragma unroll
  for (int t = 0; t < 4; ++t) {
    const int row = 32 * wave + 8 * t + rl;
    const char* g = (const char*)(qg + (size_t)(b * L_ + l0 + row) * D_ + h * HD_ + ((csel ^ (row & 7)) << 3));
    __builtin_amdgcn_global_load_lds(
        (const __attribute__((address_space(1))) void*)g,
        (__attribute__((address_space(3))) void*)(smem + QS_OFF + (32 * wave + 8 * t) * 128 + lane * 16),
        16, 0, 0);
  }
  __syncthreads();

  // Q A-frags held in registers (rows 32w+16tm+mlane)
  bf16x8 qa[2][2];
#pragma unroll
  for (int tm = 0; tm < 2; ++tm)
#pragma unroll
    for (int kk = 0; kk < 2; ++kk) {
      const int row = 32 * wave + 16 * tm + mlane;
      qa[tm][kk] = *(const bf16x8*)(smem + QS_OFF + row * 128 + (((4 * kk + kgrp) ^ (row & 7)) << 4));
    }

  // decay row factors gamma^n
  float rq[2][4];
#pragma unroll
  for (int tm = 0; tm < 2; ++tm)
#pragma unroll
    for (int r = 0; r < 4; ++r) {
      const int n = l0 + 32 * wave + 16 * tm + kgrp * 4 + r;
      rq[tm][r] = exp2f((float)n * lg2g);
    }

  f32x4 racc[2][4] = {};
  const int ntile = 2 * blockIdx.x + 2;

  for (int it = 0; it < ntile; ++it) {
    const int s0 = it * 64;
    __syncthreads();
    // ---- stage K tile (s0..s0+63) and Vt tile ----
#pragma unroll
    for (int t = 0; t < 2; ++t) {
      const int row = 16 * wave + 8 * t + rl;          // 0..63
      const char* gk = (const char*)(kg + (size_t)(b * L_ + s0 + row) * D_ + h * HD_ + ((csel ^ (row & 7)) << 3));
      __builtin_amdgcn_global_load_lds(
          (const __attribute__((address_space(1))) void*)gk,
          (__attribute__((address_space(3))) void*)(smem + KS_OFF + (16 * wave + 8 * t) * 128 + lane * 16),
          16, 0, 0);
      const char* gv = (const char*)(vtg + (size_t)(h * HD_ + row) * M_ + b * L_ + s0 + ((csel ^ (row & 7)) << 3));
      __builtin_amdgcn_global_load_lds(
          (const __attribute__((address_space(1))) void*)gv,
          (__attribute__((address_space(3))) void*)(smem + VT_OFF + (16 * wave + 8 * t) * 128 + lane * 16),
          16, 0, 0);
    }
    __syncthreads();

    if (s0 <= l0 + 32 * wave + 31) {
      // B-frags for K and Vt (shared across tm)
      bf16x8 kb[4][2], vb[4][2];
#pragma unroll
      for (int tn = 0; tn < 4; ++tn)
#pragma unroll
        for (int kk = 0; kk < 2; ++kk) {
          const int row = 16 * tn + mlane;
          const int sw = ((4 * kk + kgrp) ^ (row & 7)) << 4;
          kb[tn][kk] = *(const bf16x8*)(smem + KS_OFF + row * 128 + sw);
          vb[tn][kk] = *(const bf16x8*)(smem + VT_OFF + row * 128 + sw);
        }
      float cs[4];
#pragma unroll
      for (int tn = 0; tn < 4; ++tn)
        cs[tn] = exp2f(-(float)(s0 + 16 * tn + mlane) * lg2g);

#pragma unroll
      for (int tm = 0; tm < 2; ++tm) {
        const int rowmin = l0 + 32 * wave + 16 * tm;
        if (s0 > rowmin + 15) continue;
        // S = Q K^T
        f32x4 sf[4];
#pragma unroll
        for (int tn = 0; tn < 4; ++tn) {
          f32x4 z = {};
          z = __builtin_amdgcn_mfma_f32_16x16x32_bf16(qa[tm][0], kb[tn][0], z, 0, 0, 0);
          sf[tn] = __builtin_amdgcn_mfma_f32_16x16x32_bf16(qa[tm][1], kb[tn][1], z, 0, 0, 0);
        }
        // decay, cvt, write P to LDS (swizzled scalar writes)
        const bool needMask = (s0 + 63 >= rowmin);
#pragma unroll
        for (int tn = 0; tn < 4; ++tn)
#pragma unroll
          for (int r = 0; r < 4; ++r) {
            float w = rq[tm][r] * cs[tn];
            if (needMask) {
              const int d = rowmin + kgrp * 4 + r - (s0 + 16 * tn + mlane);
              w = (d >= 0) ? w : 0.0f;
            }
            const unsigned short pv = f2b(sf[tn][r] * w);
            const int prow = 32 * wave + 16 * tm + kgrp * 4 + r;
            const int pcol = 16 * tn + mlane;
            *(unsigned short*)(smem + PS_OFF + prow * 128 +
                               ((((pcol >> 3) ^ (prow & 7))) << 4) + ((pcol & 7) << 1)) = pv;
          }
        // PV
        bf16x8 pa[2];
#pragma unroll
        for (int kk = 0; kk < 2; ++kk) {
          const int row = 32 * wave + 16 * tm + mlane;
          pa[kk] = *(const bf16x8*)(smem + PS_OFF + row * 128 + (((4 * kk + kgrp) ^ (row & 7)) << 4));
        }
#pragma unroll
        for (int tn = 0; tn < 4; ++tn) {
          racc[tm][tn] = __builtin_amdgcn_mfma_f32_16x16x32_bf16(pa[0], vb[tn][0], racc[tm][tn], 0, 0, 0);
          racc[tm][tn] = __builtin_amdgcn_mfma_f32_16x16x32_bf16(pa[1], vb[tn][1], racc[tm][tn], 0, 0, 0);
        }
      }
    }
  }

  // ---- GroupNorm over 64 cols + gate multiply, bf16 out ----
#pragma unroll
  for (int tm = 0; tm < 2; ++tm)
#pragma unroll
    for (int r = 0; r < 4; ++r) {
      float vv[4], sm = 0.0f, sq = 0.0f;
#pragma unroll
      for (int tn = 0; tn < 4; ++tn) {
        vv[tn] = racc[tm][tn][r];
        sm += vv[tn]; sq += vv[tn] * vv[tn];
      }
#pragma unroll
      for (int off = 1; off < 16; off <<= 1) {
        sm += __shfl_xor(sm, off);
        sq += __shfl_xor(sq, off);
      }
      const float mu = sm * (1.0f / 64.0f);
      float var = sq * (1.0f / 64.0f) - mu * mu;
      var = fmaxf(var, 0.0f);
      const float inv = rsqrtf(var + 1e-5f);
      const int row = l0 + 32 * wave + 16 * tm + kgrp * 4 + r;
      const size_t base = (size_t)(b * L_ + row) * D_ + h * HD_;
#pragma unroll
      for (int tn = 0; tn < 4; ++tn) {
        const int c = 16 * tn + mlane;
        const float g = b2f(gate[base + c]);
        Abuf[base + c] = f2b((vv[tn] - mu) * inv * g);
      }
    }
}

// ---------------------------------------------------------------------------
extern "C" void kernel_launch(void* const* d_in, const int* in_sizes, int n_in,
                              void* d_out, int out_size, void* d_ws, size_t ws_size,
                              hipStream_t stream)
{
  const float* query = (const float*)d_in[0];
  const float* key   = (const float*)d_in[1];
  const float* value = (const float*)d_in[2];
  const float* W_Q   = (const float*)d_in[3];
  const float* W_K   = (const float*)d_in[4];
  const float* W_V   = (const float*)d_in[5];
  const float* g_w   = (const float*)d_in[6];
  const float* g_b   = (const float*)d_in[7];
  const float* out_w = (const float*)d_in[8];
  const float* out_b = (const float*)d_in[9];
  float* out = (float*)d_out;

  const size_t MD = (size_t)M_ * D_;
  const size_t DD = (size_t)D_ * D_;
  unsigned short* Xqb   = (unsigned short*)d_ws;
  unsigned short* Xkb   = Xqb + MD;
  unsigned short* Xvb   = Xkb + MD;
  unsigned short* WQt   = Xvb + MD;
  unsigned short* WKt   = WQt + DD;
  unsigned short* WVt   = WKt + DD;
  unsigned short* gwb   = WVt + DD;
  unsigned short* owb   = gwb + DD;
  unsigned short* gateB = owb + DD;
  unsigned short* qb2   = gateB + MD;
  unsigned short* kb2   = qb2 + MD;
  unsigned short* vtg   = kb2 + MD;
  unsigned short* AbufB = vtg + MD;
  float* ctq = (float*)(AbufB + MD);
  float* stq = ctq + 2048 * 32;
  float* ctk = stq + 2048 * 32;
  float* stk = ctk + 2048 * 32;

  cast_f2b_kernel<<<4096, 256, 0, stream>>>(query, Xqb, (int)MD);
  cast_f2b_kernel<<<4096, 256, 0, stream>>>(key,   Xkb, (int)MD);
  cast_f2b_kernel<<<4096, 256, 0, stream>>>(value, Xvb, (int)MD);
  cast_f2b_kernel<<<1024, 256, 0, stream>>>(g_w,   gwb, (int)DD);
  cast_f2b_kernel<<<1024, 256, 0, stream>>>(out_w, owb, (int)DD);
  transpose_w_kernel<<<dim3(32, 2, 16), dim3(32, 8), 0, stream>>>(W_Q, WQt);
  transpose_w_kernel<<<dim3(32, 2, 16), dim3(32, 8), 0, stream>>>(W_K, WKt);
  transpose_w_kernel<<<dim3(32, 2, 16), dim3(32, 8), 0, stream>>>(W_V, WVt);
  xpos_tables_kernel<<<2048, 32, 0, stream>>>(ctq, stq, ctk, stk);

  dim3 gg(M_ / 128, D_ / 64);
  // q, k projections with fused xpos -> bf16 (B*L, D)
  gemm_bf16_kernel<<<gg, 256, 0, stream>>>(Xqb, WQt, nullptr, qb2, ctq, stq, nullptr, 1, D_);
  gemm_bf16_kernel<<<gg, 256, 0, stream>>>(Xkb, WKt, nullptr, kb2, ctk, stk, nullptr, 2, D_);
  // v projection, operand-swapped -> writes V^T directly: vt[(h*64+e)][b*2048+l]
  gemm_bf16_kernel<<<dim3(D_ / 128, M_ / 64), 256, 0, stream>>>(WVt, Xvb, nullptr, vtg, nullptr, nullptr, nullptr, 0, M_);
  // gate
  gemm_bf16_kernel<<<gg, 256, 0, stream>>>(Xqb, gwb, nullptr, gateB, nullptr, nullptr, g_b, 3, D_);

  attn_mfma_kernel<<<dim3(L_ / 128, B_ * H_), 256, 0, stream>>>(qb2, kb2, vtg, gateB, AbufB);

  gemm_bf16_kernel<<<gg, 256, 0, stream>>>(AbufB, owb, out, nullptr, nullptr, nullptr, out_b, 4, D_);
}

// Round 4
// 267.785 us; speedup vs baseline: 5.0503x; 1.2271x over previous
//
#include <hip/hip_runtime.h>
#include <cstdint>

#define B_  2
#define L_  2048
#define D_  1024
#define H_  16
#define HD_ 64
#define M_  (B_*L_)   // 4096

#define MD  4194304u   // M_*D_
#define DD  1048576u   // D_*D_

// workspace layout (element offsets, unsigned short)
#define OFF_XQB  0u
#define OFF_XKB  (MD)
#define OFF_XVB  (2u*MD)
#define OFF_WQT  (3u*MD)
#define OFF_WKT  (3u*MD + DD)
#define OFF_WVT  (3u*MD + 2u*DD)
#define OFF_GWB  (3u*MD + 3u*DD)
#define OFF_OWB  (3u*MD + 4u*DD)
#define OFF_GATE (3u*MD + 5u*DD)
#define OFF_QB2  (OFF_GATE + MD)
#define OFF_KB2  (OFF_QB2 + MD)
#define OFF_VTG  (OFF_KB2 + MD)
#define OFF_ABUF (OFF_VTG + MD)
#define OFF_F32  (OFF_ABUF + MD)   // float region starts here (cast to float*)

typedef __attribute__((ext_vector_type(8))) short bf16x8;
typedef __attribute__((ext_vector_type(4))) float f32x4;

__device__ __forceinline__ unsigned short f2b(float x){
  union { float f; unsigned u; } a; a.f = x;
  unsigned r = a.u + 0x7FFFu + ((a.u >> 16) & 1u);
  return (unsigned short)(r >> 16);
}
__device__ __forceinline__ float b2f(unsigned short u){
  union { unsigned u; float f; } a; a.u = ((unsigned)u) << 16; return a.f;
}

// ---------------------------------------------------------------------------
// merged fp32->bf16 cast for query/key/value/g_w/out_w (one launch)
// total elements = 3*MD + 2*DD; grid 14336 x 256, 4 elem/thread
// ---------------------------------------------------------------------------
__global__ __launch_bounds__(256) void cast_all_kernel(
    const float* __restrict__ q, const float* __restrict__ k,
    const float* __restrict__ v, const float* __restrict__ gw,
    const float* __restrict__ ow, unsigned short* __restrict__ ws)
{
  size_t i = ((size_t)blockIdx.x * 256 + threadIdx.x) * 4;
  const float* src; unsigned short* dst;
  if (i < MD)            { src = q  + i;              dst = ws + OFF_XQB + i; }
  else if (i < 2u*MD)    { src = k  + (i - MD);       dst = ws + OFF_XKB + (i - MD); }
  else if (i < 3u*MD)    { src = v  + (i - 2u*MD);    dst = ws + OFF_XVB + (i - 2u*MD); }
  else if (i < 3u*MD+DD) { src = gw + (i - 3u*MD);    dst = ws + OFF_GWB + (i - 3u*MD); }
  else                   { src = ow + (i - 3u*MD-DD); dst = ws + OFF_OWB + (i - 3u*MD - DD); }
  float4 vv = *(const float4*)src;
  ushort4 o; o.x = f2b(vv.x); o.y = f2b(vv.y); o.z = f2b(vv.z); o.w = f2b(vv.w);
  *(ushort4*)dst = o;
}

// ---------------------------------------------------------------------------
// merged weight transpose: W (h,d,e) fp32 -> Bt[(h*64+e)][d] bf16, 3 weights
// grid (32, 2, 48), block (32, 8);  z: w = z/16, h = z%16
// ---------------------------------------------------------------------------
__global__ void transpose_w_kernel(const float* __restrict__ WQ,
                                   const float* __restrict__ WK,
                                   const float* __restrict__ WV,
                                   unsigned short* __restrict__ ws)
{
  __shared__ float t[32][33];
  const int z = blockIdx.z, w = z >> 4, h = z & 15;
  const float* in = (w == 0) ? WQ : (w == 1) ? WK : WV;
  unsigned short* out = ws + ((w == 0) ? OFF_WQT : (w == 1) ? OFF_WKT : OFF_WVT);
  const int d0 = blockIdx.x * 32, e0 = blockIdx.y * 32;
  const int x = threadIdx.x;
  for (int yy = threadIdx.y; yy < 32; yy += 8)
    t[yy][x] = in[((size_t)h * D_ + d0 + yy) * HD_ + e0 + x];
  __syncthreads();
  for (int yy = threadIdx.y; yy < 32; yy += 8)
    out[((size_t)h * HD_ + e0 + yy) * D_ + d0 + x] = f2b(t[x][yy]);
}

// ---------------------------------------------------------------------------
// xPos tables (in float region of ws): ctq | stq | ctk | stk, 65536 floats each
// ---------------------------------------------------------------------------
__global__ void xpos_tables_kernel(float* __restrict__ fb)
{
  const int l = blockIdx.x, i = threadIdx.x;
  const float base = (2.0f * (float)i + 0.4f * (float)HD_) / (1.4f * (float)HD_);
  const float p = (float)(l - L_ / 2) * (1.0f / 512.0f);
  const float sc = exp2f(p * log2f(base));
  const float invf = exp2f(-(float)i * (13.287712379549449f / 32.0f));
  float s, c; sincosf((float)l * invf, &s, &c);
  fb[          l * 32 + i] = c * sc;
  fb[ 65536 +  l * 32 + i] = s * sc;
  const float is = 1.0f / sc;
  fb[131072 +  l * 32 + i] = c * is;
  fb[196608 +  l * 32 + i] = s * is;
}

// ---------------------------------------------------------------------------
// shared GEMM body: C(M,N) tile 128x64, K=1024, bf16 MFMA.
// modes: 0 plain->bf16; 1/2 xpos->bf16; 3 silu+bias->bf16; 4 +bias->fp32
// ---------------------------------------------------------------------------
__device__ __forceinline__ void gemm_body(
    const unsigned short* __restrict__ A, const unsigned short* __restrict__ Bt,
    float* __restrict__ outF, unsigned short* __restrict__ outB,
    const float* __restrict__ ct, const float* __restrict__ st,
    const float* __restrict__ bias, int mode, int ldc, int M0, int N0,
    short* As, short* Bs)
{
  const int tid = threadIdx.x;
  const int wave = tid >> 6, lane = tid & 63;
  const int wm = wave & 1, wn = wave >> 1;
  const int mlane = lane & 15, kgrp = lane >> 4;
  const int arow0 = wave * 32 + (lane >> 2);
  const int akc   = lane & 3;
  const int brow  = wave * 16 + (lane >> 2);
  const char* Ab = (const char*)A;
  const char* Bb = (const char*)Bt;

  f32x4 acc[4][2] = {};

  for (int K0 = 0; K0 < 1024; K0 += 32) {
    __syncthreads();
#pragma unroll
    for (int t = 0; t < 2; ++t) {
      const char* g = Ab + ((size_t)(M0 + arow0 + t * 16) * 1024 + K0 + akc * 8) * 2;
      __builtin_amdgcn_global_load_lds(
          (const __attribute__((address_space(1))) void*)g,
          (__attribute__((address_space(3))) void*)((char*)As + (wave * 2 + t) * 1024 + lane * 16),
          16, 0, 0);
    }
    {
      const char* g = Bb + ((size_t)(N0 + brow) * 1024 + K0 + akc * 8) * 2;
      __builtin_amdgcn_global_load_lds(
          (const __attribute__((address_space(1))) void*)g,
          (__attribute__((address_space(3))) void*)((char*)Bs + wave * 1024 + lane * 16),
          16, 0, 0);
    }
    __syncthreads();
    bf16x8 af[4], bfr[2];
#pragma unroll
    for (int tm = 0; tm < 4; ++tm)
      af[tm] = *(const bf16x8*)&As[(wm * 64 + tm * 16 + mlane) * 32 + kgrp * 8];
#pragma unroll
    for (int tn = 0; tn < 2; ++tn)
      bfr[tn] = *(const bf16x8*)&Bs[(wn * 32 + tn * 16 + mlane) * 32 + kgrp * 8];
#pragma unroll
    for (int tm = 0; tm < 4; ++tm)
#pragma unroll
      for (int tn = 0; tn < 2; ++tn)
        acc[tm][tn] = __builtin_amdgcn_mfma_f32_16x16x32_bf16(af[tm], bfr[tn], acc[tm][tn], 0, 0, 0);
  }

#pragma unroll
  for (int tm = 0; tm < 4; ++tm)
#pragma unroll
    for (int tn = 0; tn < 2; ++tn) {
      f32x4 v = acc[tm][tn];
#pragma unroll
      for (int r = 0; r < 4; ++r) {
        const int grow = M0 + wm * 64 + tm * 16 + (lane >> 4) * 4 + r;
        const int gcol = N0 + wn * 32 + tn * 16 + mlane;
        float val = v[r];
        if (mode == 1 || mode == 2) {
          const float partner = __shfl_xor(val, 1);
          const int l = grow & (L_ - 1);
          const int i = (gcol >> 1) & 31;
          const float c = ct[l * 32 + i], s = st[l * 32 + i];
          val = (gcol & 1) ? (val * c + partner * s) : (val * c - partner * s);
          outB[(size_t)grow * ldc + gcol] = f2b(val);
        } else if (mode == 0) {
          outB[(size_t)grow * ldc + gcol] = f2b(val);
        } else if (mode == 3) {
          const float x = val + bias[gcol];
          outB[(size_t)grow * ldc + gcol] = f2b(x / (1.0f + expf(-x)));
        } else {
          outF[(size_t)grow * ldc + gcol] = val + bias[gcol];
        }
      }
    }
}

// ---------------------------------------------------------------------------
// merged q/k/v/gate GEMMs: grid (512, 4), blockIdx.y selects the GEMM.
// z=0: q-proj (xpos), z=1: k-proj (xpos), z=2: v-proj operand-swapped -> V^T,
// z=3: gate (silu+bias)
// ---------------------------------------------------------------------------
__global__ __launch_bounds__(256) void gemm4_kernel(
    unsigned short* __restrict__ ws, const float* __restrict__ g_b)
{
  __shared__ __align__(16) short As[128 * 32];
  __shared__ __align__(16) short Bs[64 * 32];
  const int z = blockIdx.y, bx = blockIdx.x;
  float* fb = (float*)(ws + OFF_F32);
  const unsigned short *A, *Bt; unsigned short* outB;
  const float *ct = nullptr, *st = nullptr, *bias = nullptr;
  int mode, ldc, M0, N0;
  if (z == 0) {
    A = ws + OFF_XQB; Bt = ws + OFF_WQT; outB = ws + OFF_QB2;
    ct = fb; st = fb + 65536; mode = 1; ldc = D_;
    M0 = (bx & 31) * 128; N0 = (bx >> 5) * 64;
  } else if (z == 1) {
    A = ws + OFF_XKB; Bt = ws + OFF_WKT; outB = ws + OFF_KB2;
    ct = fb + 131072; st = fb + 196608; mode = 2; ldc = D_;
    M0 = (bx & 31) * 128; N0 = (bx >> 5) * 64;
  } else if (z == 2) {
    A = ws + OFF_WVT; Bt = ws + OFF_XVB; outB = ws + OFF_VTG;
    mode = 0; ldc = M_;
    M0 = (bx & 7) * 128; N0 = (bx >> 3) * 64;
  } else {
    A = ws + OFF_XQB; Bt = ws + OFF_GWB; outB = ws + OFF_GATE;
    bias = g_b; mode = 3; ldc = D_;
    M0 = (bx & 31) * 128; N0 = (bx >> 5) * 64;
  }
  gemm_body(A, Bt, nullptr, outB, ct, st, bias, mode, ldc, M0, N0, As, Bs);
}

// final GEMM: out = Abuf @ owb^T + out_b (fp32 out)
__global__ __launch_bounds__(256) void gemm_final_kernel(
    unsigned short* __restrict__ ws, const float* __restrict__ out_b,
    float* __restrict__ out)
{
  __shared__ __align__(16) short As[128 * 32];
  __shared__ __align__(16) short Bs[64 * 32];
  gemm_body(ws + OFF_ABUF, ws + OFF_OWB, out, nullptr, nullptr, nullptr,
            out_b, 4, D_, blockIdx.x * 128, blockIdx.y * 64, As, Bs);
}

// ---------------------------------------------------------------------------
// MFMA retention attention + fused GroupNorm + gate.
// grid 512 (1D): bh = id&31, u = id>>5, x = u<8 ? u : 23-u  (balance pairing:
// co-resident blocks id, id+256 get complementary work 2x+2 + 2(15-x)+2 = 34)
// S^T trick: mfma(K_frag, Q_frag) -> lane holds 4 consecutive s for fixed n
// -> packed b64 P-writes.
// ---------------------------------------------------------------------------
#define QS_OFF 0
#define KS_OFF 16384
#define VT_OFF 24576
#define PS_OFF 32768

__global__ __launch_bounds__(256) void attn_mfma_kernel(
    const unsigned short* __restrict__ qg, const unsigned short* __restrict__ kg,
    const unsigned short* __restrict__ vtg, const unsigned short* __restrict__ gate,
    unsigned short* __restrict__ Abuf)
{
  __shared__ __align__(16) char smem[49152];
  const int tid = threadIdx.x, wave = tid >> 6, lane = tid & 63;
  const int mlane = lane & 15, kgrp = lane >> 4;
  const int id = blockIdx.x;
  const int bh = id & 31;
  const int u  = id >> 5;
  const int xq = (u < 8) ? u : (23 - u);
  const int l0 = xq * 128;
  const int b = bh >> 4, h = bh & 15;

  const float lo   = -3.4657359027997265f;
  const float step = -0.1848392481493187f;
  const float gamma = 1.0f - expf(lo + (float)h * step);
  const float lg2g  = log2f(gamma);
  const float g1    = exp2f(-lg2g);           // 1/gamma
  const float gmr[4] = {1.0f, g1, g1 * g1, g1 * g1 * g1};

  const int rl = lane >> 3, csel = lane & 7;

  // ---- stage Q (128 x 64 bf16, XOR-chunk swizzled) ----
#pragma unroll
  for (int t = 0; t < 4; ++t) {
    const int row = 32 * wave + 8 * t + rl;
    const char* g = (const char*)(qg + (size_t)(b * L_ + l0 + row) * D_ + h * HD_ + ((csel ^ (row & 7)) << 3));
    __builtin_amdgcn_global_load_lds(
        (const __attribute__((address_space(1))) void*)g,
        (__attribute__((address_space(3))) void*)(smem + QS_OFF + (32 * wave + 8 * t) * 128 + lane * 16),
        16, 0, 0);
  }
  __syncthreads();

  bf16x8 qa[2][2];
#pragma unroll
  for (int tm = 0; tm < 2; ++tm)
#pragma unroll
    for (int kk = 0; kk < 2; ++kk) {
      const int row = 32 * wave + 16 * tm + mlane;
      qa[tm][kk] = *(const bf16x8*)(smem + QS_OFF + row * 128 + (((4 * kk + kgrp) ^ (row & 7)) << 4));
    }

  // gamma^n for this lane's Q-row (n column in S^T layout)
  float rqm[2];
#pragma unroll
  for (int tm = 0; tm < 2; ++tm)
    rqm[tm] = exp2f((float)(l0 + 32 * wave + 16 * tm + mlane) * lg2g);

  f32x4 racc[2][4] = {};
  const int ntile = 2 * xq + 2;

  for (int it = 0; it < ntile; ++it) {
    const int s0 = it * 64;
    __syncthreads();
#pragma unroll
    for (int t = 0; t < 2; ++t) {
      const int row = 16 * wave + 8 * t + rl;
      const char* gk = (const char*)(kg + (size_t)(b * L_ + s0 + row) * D_ + h * HD_ + ((csel ^ (row & 7)) << 3));
      __builtin_amdgcn_global_load_lds(
          (const __attribute__((address_space(1))) void*)gk,
          (__attribute__((address_space(3))) void*)(smem + KS_OFF + (16 * wave + 8 * t) * 128 + lane * 16),
          16, 0, 0);
      const char* gv = (const char*)(vtg + (size_t)(h * HD_ + row) * M_ + b * L_ + s0 + ((csel ^ (row & 7)) << 3));
      __builtin_amdgcn_global_load_lds(
          (const __attribute__((address_space(1))) void*)gv,
          (__attribute__((address_space(3))) void*)(smem + VT_OFF + (16 * wave + 8 * t) * 128 + lane * 16),
          16, 0, 0);
    }
    __syncthreads();

    if (s0 <= l0 + 32 * wave + 31) {
      bf16x8 kb[4][2], vb[4][2];
#pragma unroll
      for (int tn = 0; tn < 4; ++tn)
#pragma unroll
        for (int kk = 0; kk < 2; ++kk) {
          const int row = 16 * tn + mlane;
          const int sw = ((4 * kk + kgrp) ^ (row & 7)) << 4;
          kb[tn][kk] = *(const bf16x8*)(smem + KS_OFF + row * 128 + sw);
          vb[tn][kk] = *(const bf16x8*)(smem + VT_OFF + row * 128 + sw);
        }
      // gamma^{-(s0+16tn+4kgrp)}
      float csb[4];
#pragma unroll
      for (int tn = 0; tn < 4; ++tn)
        csb[tn] = exp2f(-(float)(s0 + 16 * tn + 4 * kgrp) * lg2g);

#pragma unroll
      for (int tm = 0; tm < 2; ++tm) {
        const int rowmin = l0 + 32 * wave + 16 * tm;
        if (s0 > rowmin + 15) continue;
        // S^T = K . Q^T : lane -> col n = mlane, rows s = 16tn + 4kgrp + r
        f32x4 sf[4];
#pragma unroll
        for (int tn = 0; tn < 4; ++tn) {
          f32x4 z = {};
          z = __builtin_amdgcn_mfma_f32_16x16x32_bf16(kb[tn][0], qa[tm][0], z, 0, 0, 0);
          sf[tn] = __builtin_amdgcn_mfma_f32_16x16x32_bf16(kb[tn][1], qa[tm][1], z, 0, 0, 0);
        }
        const int nrow = rowmin + mlane;
        const bool needMask = (s0 + 63 >= rowmin);
        const int prow = 32 * wave + 16 * tm + mlane;
#pragma unroll
        for (int tn = 0; tn < 4; ++tn) {
          const float wbase = rqm[tm] * csb[tn];
          const int sbase = s0 + 16 * tn + 4 * kgrp;
          float vv[4];
#pragma unroll
          for (int r = 0; r < 4; ++r) {
            float w = wbase * gmr[r];
            if (needMask) w = (nrow - (sbase + r) >= 0) ? w : 0.0f;
            vv[r] = sf[tn][r] * w;
          }
          uint2 pk;
          pk.x = (unsigned)f2b(vv[0]) | ((unsigned)f2b(vv[1]) << 16);
          pk.y = (unsigned)f2b(vv[2]) | ((unsigned)f2b(vv[3]) << 16);
          *(uint2*)(smem + PS_OFF + prow * 128 +
                    (((2 * tn + (kgrp >> 1)) ^ (prow & 7)) << 4) + ((kgrp & 1) << 3)) = pk;
        }
        // PV (P rows written and read by the same wave -> no barrier)
        bf16x8 pa[2];
#pragma unroll
        for (int kk = 0; kk < 2; ++kk) {
          const int row = 32 * wave + 16 * tm + mlane;
          pa[kk] = *(const bf16x8*)(smem + PS_OFF + row * 128 + (((4 * kk + kgrp) ^ (row & 7)) << 4));
        }
#pragma unroll
        for (int tn = 0; tn < 4; ++tn) {
          racc[tm][tn] = __builtin_amdgcn_mfma_f32_16x16x32_bf16(pa[0], vb[tn][0], racc[tm][tn], 0, 0, 0);
          racc[tm][tn] = __builtin_amdgcn_mfma_f32_16x16x32_bf16(pa[1], vb[tn][1], racc[tm][tn], 0, 0, 0);
        }
      }
    }
  }

  // ---- GroupNorm + gate, bf16 out ----
#pragma unroll
  for (int tm = 0; tm < 2; ++tm)
#pragma unroll
    for (int r = 0; r < 4; ++r) {
      float vv[4], sm = 0.0f, sq = 0.0f;
#pragma unroll
      for (int tn = 0; tn < 4; ++tn) {
        vv[tn] = racc[tm][tn][r];
        sm += vv[tn]; sq += vv[tn] * vv[tn];
      }
#pragma unroll
      for (int off = 1; off < 16; off <<= 1) {
        sm += __shfl_xor(sm, off);
        sq += __shfl_xor(sq, off);
      }
      const float mu = sm * (1.0f / 64.0f);
      float var = sq * (1.0f / 64.0f) - mu * mu;
      var = fmaxf(var, 0.0f);
      const float inv = rsqrtf(var + 1e-5f);
      const int row = l0 + 32 * wave + 16 * tm + kgrp * 4 + r;
      const size_t base = (size_t)(b * L_ + row) * D_ + h * HD_;
#pragma unroll
      for (int tn = 0; tn < 4; ++tn) {
        const int c = 16 * tn + mlane;
        const float g = b2f(gate[base + c]);
        Abuf[base + c] = f2b((vv[tn] - mu) * inv * g);
      }
    }
}

// ---------------------------------------------------------------------------
extern "C" void kernel_launch(void* const* d_in, const int* in_sizes, int n_in,
                              void* d_out, int out_size, void* d_ws, size_t ws_size,
                              hipStream_t stream)
{
  const float* query = (const float*)d_in[0];
  const float* key   = (const float*)d_in[1];
  const float* value = (const float*)d_in[2];
  const float* W_Q   = (const float*)d_in[3];
  const float* W_K   = (const float*)d_in[4];
  const float* W_V   = (const float*)d_in[5];
  const float* g_b   = (const float*)d_in[7];
  const float* out_b = (const float*)d_in[9];
  float* out = (float*)d_out;

  unsigned short* ws = (unsigned short*)d_ws;
  float* fb = (float*)(ws + OFF_F32);

  cast_all_kernel<<<14336, 256, 0, stream>>>(query, key, value,
                                             (const float*)d_in[6],
                                             (const float*)d_in[8], ws);
  transpose_w_kernel<<<dim3(32, 2, 48), dim3(32, 8), 0, stream>>>(W_Q, W_K, W_V, ws);
  xpos_tables_kernel<<<2048, 32, 0, stream>>>(fb);

  gemm4_kernel<<<dim3(512, 4), 256, 0, stream>>>(ws, g_b);

  attn_mfma_kernel<<<512, 256, 0, stream>>>(ws + OFF_QB2, ws + OFF_KB2,
                                            ws + OFF_VTG, ws + OFF_GATE,
                                            ws + OFF_ABUF);

  gemm_final_kernel<<<dim3(M_ / 128, D_ / 64), 256, 0, stream>>>(ws, out_b, out);
}